// Round 1
// baseline (148.961 us; speedup 1.0000x reference)
//
#include <hip/hip_runtime.h>
#include <hip/hip_fp16.h>

// Problem geometry (fixed by the reference)
constexpr int K    = 512;     // inner dim
constexpr int ROWS = 1024;    // B*T = 4*256
constexpr int COLS = 512;     // OUT
constexpr int NX   = ROWS * K;   // decoded x element count
constexpr int NW   = COLS * K;   // decoded w element count

// ---------------------------------------------------------------------------
// Kernel 1: decode pulse bits -> exact fp16 value stored as fp32.
// ws layout: [0, NX) = x values ([row][k]); [NX, NX+NW) = w values ([col][k]).
// ---------------------------------------------------------------------------
__global__ __launch_bounds__(256) void decode_k(const float* __restrict__ xp,
                                                const float* __restrict__ wp,
                                                float* __restrict__ dec) {
    const int e = blockIdx.x * 256 + threadIdx.x;   // grid sized exactly
    const float4* s4;
    if (e < NX) s4 = (const float4*)(xp + (size_t)e * 16);
    else        s4 = (const float4*)(wp + (size_t)(e - NX) * 16);
    const float4 v0 = s4[0];
    const float4 v1 = s4[1];
    const float4 v2 = s4[2];
    const float4 v3 = s4[3];
    unsigned u = 0;
    u |= (unsigned)(v0.x > 0.5f) << 0;
    u |= (unsigned)(v0.y > 0.5f) << 1;
    u |= (unsigned)(v0.z > 0.5f) << 2;
    u |= (unsigned)(v0.w > 0.5f) << 3;
    u |= (unsigned)(v1.x > 0.5f) << 4;
    u |= (unsigned)(v1.y > 0.5f) << 5;
    u |= (unsigned)(v1.z > 0.5f) << 6;
    u |= (unsigned)(v1.w > 0.5f) << 7;
    u |= (unsigned)(v2.x > 0.5f) << 8;
    u |= (unsigned)(v2.y > 0.5f) << 9;
    u |= (unsigned)(v2.z > 0.5f) << 10;
    u |= (unsigned)(v2.w > 0.5f) << 11;
    u |= (unsigned)(v3.x > 0.5f) << 12;
    u |= (unsigned)(v3.y > 0.5f) << 13;
    u |= (unsigned)(v3.z > 0.5f) << 14;
    u |= (unsigned)(v3.w > 0.5f) << 15;
    dec[e] = __half2float(__ushort_as_half((unsigned short)u));
}

// ---------------------------------------------------------------------------
// Kernel 2: GEMM with bit-exact sequential fp32 accumulation + fp16 RNE
// conversion + pulse re-encode.
// Block: 256 threads = 4 waves. Wave w owns rows row0..row0+7 (8 rows),
// lane = output column within the 64-col block. acc[8] per lane.
// B tile (w values) staged in LDS; A values are wave-uniform -> scalar loads.
// ---------------------------------------------------------------------------
__global__ __launch_bounds__(256) void gemm_k(const float* __restrict__ dec,
                                              float* __restrict__ out) {
    const float* __restrict__ xv = dec;        // [ROWS][K]
    const float* __restrict__ wv = dec + NX;   // [COLS][K]

    __shared__ float Bs[64][68];               // +4 pad: even bank spread for b128

    const int tid  = threadIdx.x;
    const int lane = tid & 63;
    const int wid  = __builtin_amdgcn_readfirstlane(tid >> 6);   // wave id 0..3
    const int col0 = blockIdx.x * 64;          // gridDim.x = 8
    const int row0 = blockIdx.y * 32 + wid * 8;// gridDim.y = 32

    float acc[8] = {0.f, 0.f, 0.f, 0.f, 0.f, 0.f, 0.f, 0.f};

    // staging map: 4 threads per column, 16 k's each (4 float4 loads)
    const int scol = tid >> 2;                 // 0..63
    const int skq  = (tid & 3) << 4;           // 0,16,32,48
    const float* wsrc = wv + (size_t)(col0 + scol) * K + skq;

    for (int k0 = 0; k0 < K; k0 += 64) {
        const float4 t0 = *(const float4*)(wsrc + k0 + 0);
        const float4 t1 = *(const float4*)(wsrc + k0 + 4);
        const float4 t2 = *(const float4*)(wsrc + k0 + 8);
        const float4 t3 = *(const float4*)(wsrc + k0 + 12);
        __syncthreads();   // previous tile fully consumed before overwrite
        *(float4*)&Bs[scol][skq + 0]  = t0;
        *(float4*)&Bs[scol][skq + 4]  = t1;
        *(float4*)&Bs[scol][skq + 8]  = t2;
        *(float4*)&Bs[scol][skq + 12] = t3;
        __syncthreads();

        const float* xbase = xv + k0;
        #pragma unroll
        for (int kc = 0; kc < 64; kc += 4) {
            const float4 b = *(const float4*)&Bs[lane][kc];
            #pragma unroll
            for (int r = 0; r < 8; ++r) {
                // wave-uniform address -> scalar load path
                const float4 a = *(const float4*)(xbase + (size_t)(row0 + r) * K + kc);
                float s = acc[r];
                s = fmaf(a.x, b.x, s);   // strictly ascending k: bit-exact order
                s = fmaf(a.y, b.y, s);
                s = fmaf(a.z, b.z, s);
                s = fmaf(a.w, b.w, s);
                acc[r] = s;
            }
        }
    }

    // Epilogue: fp32 -> fp16 (RNE) -> 16 pulse bits as floats.
    #pragma unroll
    for (int r = 0; r < 8; ++r) {
        const unsigned short u = __half_as_ushort(__float2half_rn(acc[r]));
        float* o = out + ((size_t)(row0 + r) * COLS + (col0 + lane)) * 16;
        float4 q;
        q.x = (float)((u >> 0) & 1);
        q.y = (float)((u >> 1) & 1);
        q.z = (float)((u >> 2) & 1);
        q.w = (float)((u >> 3) & 1);
        *(float4*)(o + 0) = q;
        q.x = (float)((u >> 4) & 1);
        q.y = (float)((u >> 5) & 1);
        q.z = (float)((u >> 6) & 1);
        q.w = (float)((u >> 7) & 1);
        *(float4*)(o + 4) = q;
        q.x = (float)((u >> 8) & 1);
        q.y = (float)((u >> 9) & 1);
        q.z = (float)((u >> 10) & 1);
        q.w = (float)((u >> 11) & 1);
        *(float4*)(o + 8) = q;
        q.x = (float)((u >> 12) & 1);
        q.y = (float)((u >> 13) & 1);
        q.z = (float)((u >> 14) & 1);
        q.w = (float)((u >> 15) & 1);
        *(float4*)(o + 12) = q;
    }
}

extern "C" void kernel_launch(void* const* d_in, const int* in_sizes, int n_in,
                              void* d_out, int out_size, void* d_ws, size_t ws_size,
                              hipStream_t stream) {
    const float* xp = (const float*)d_in[0];   // [ROWS][K][16] bits
    const float* wp = (const float*)d_in[1];   // [COLS][K][16] bits
    float* outp = (float*)d_out;               // [ROWS][COLS][16] bits
    float* dec  = (float*)d_ws;                // NX + NW floats (3 MB)

    // Kernel 1: decode both inputs to compact fp32 values.
    const int n_elem = NX + NW;                // 786432, multiple of 256
    decode_k<<<n_elem / 256, 256, 0, stream>>>(xp, wp, dec);

    // Kernel 2: tiled GEMM + encode.
    dim3 grid(COLS / 64, ROWS / 32);           // (8, 32) = 256 blocks
    gemm_k<<<grid, 256, 0, stream>>>(dec, outp);
}

// Round 2
// 126.823 us; speedup vs baseline: 1.1746x; 1.1746x over previous
//
#include <hip/hip_runtime.h>
#include <hip/hip_fp16.h>

// Problem geometry (fixed by the reference)
constexpr int K    = 512;     // inner dim
constexpr int ROWS = 1024;    // B*T = 4*256
constexpr int COLS = 512;     // OUT
constexpr int NX   = ROWS * K;   // decoded x element count
constexpr int NW   = COLS * K;   // decoded w element count

// ---------------------------------------------------------------------------
// Kernel 1: decode pulse bits -> exact fp16 value stored as fp32.
// LDS-transpose so every global load instruction is fully coalesced
// (lane stride 16 B), then each thread assembles one element's 16 bits.
// Pulse floats are exactly 0.0f/1.0f -> bit k of 1.0f's pattern: (w>>23)&1.
// ws layout: [0, NX) = x values ([row][k]); [NX, NX+NW) = w values ([col][k]).
// ---------------------------------------------------------------------------
__global__ __launch_bounds__(256) void decode_k(const float* __restrict__ xp,
                                                const float* __restrict__ wp,
                                                float* __restrict__ dec) {
    __shared__ float lds[256 * 17];          // 17-float element stride: odd -> conflict-free re-read
    const int t = threadIdx.x;
    const int ebase = blockIdx.x << 8;       // first element this block (256 elems/block)
    const float4* s4 = (ebase < NX)
        ? (const float4*)(xp + (size_t)ebase * 16)
        : (const float4*)(wp + (size_t)(ebase - NX) * 16);

    #pragma unroll
    for (int j = 0; j < 4; ++j) {
        const int f = t + (j << 8);          // float4 index: lane stride 16 B -> coalesced
        const float4 v = s4[f];
        const int e = f >> 2;                // local element
        const int q = f & 3;                 // quarter within element
        *(float4*)&lds[e * 17 + (q << 2)] = v;
    }
    __syncthreads();

    const float* m = &lds[t * 17];
    unsigned u = 0;
    #pragma unroll
    for (int k = 0; k < 16; ++k) {
        const unsigned w = __float_as_uint(m[k]);
        u |= ((w >> 23) & 1u) << k;          // 1.0f = 0x3F800000 -> bit23
    }
    dec[ebase + t] = __half2float(__ushort_as_half((unsigned short)u));
}

// ---------------------------------------------------------------------------
// Kernel 2: GEMM, bit-exact sequential fp32 accumulation (ascending k),
// then fp16 RNE + pulse re-encode.
// Block: 256 threads = 4 waves; wave owns 4 rows x 64 cols (lane = col).
// Grid (8, 64) = 512 blocks -> 2 blocks/CU, 2 waves/SIMD.
// Per 64-k tile: stage B in LDS (reg-prefetched), drain it ONCE into 64
// VGPRs per lane, then the inner body is pure {scalar A load + FMA} in
// 16-k phases -> SMEM (s_load) waits never interleave with DS waits.
// ---------------------------------------------------------------------------
__global__ __launch_bounds__(256) void gemm_k(const float* __restrict__ dec,
                                              float* __restrict__ out) {
    const float* __restrict__ xv = dec;        // [ROWS][K]
    const float* __restrict__ wv = dec + NX;   // [COLS][K]

    __shared__ float Bs[64][68];               // 68-stride: 2-way max on b128 (free)

    const int tid  = threadIdx.x;
    const int lane = tid & 63;
    const int wid  = __builtin_amdgcn_readfirstlane(tid >> 6);   // 0..3, provably uniform
    const int col0 = blockIdx.x << 6;          // gridDim.x = 8
    const int row0 = (blockIdx.y << 4) + (wid << 2);  // gridDim.y = 64; 4 rows/wave

    float acc[4] = {0.f, 0.f, 0.f, 0.f};

    // B staging map: 4 threads per column, 16 k's each (4 float4 loads)
    const int scol = tid >> 2;                 // 0..63
    const int skq  = (tid & 3) << 4;           // 0,16,32,48
    const float* wsrc = wv + (size_t)(col0 + scol) * K + skq;

    // prefetch first B tile into registers
    float4 t0 = *(const float4*)(wsrc + 0);
    float4 t1 = *(const float4*)(wsrc + 4);
    float4 t2 = *(const float4*)(wsrc + 8);
    float4 t3 = *(const float4*)(wsrc + 12);

    const float* arow = xv + (size_t)row0 * K; // wave-uniform base

    for (int k0 = 0; k0 < K; k0 += 64) {
        __syncthreads();                       // previous tile fully consumed
        *(float4*)&Bs[scol][skq + 0]  = t0;
        *(float4*)&Bs[scol][skq + 4]  = t1;
        *(float4*)&Bs[scol][skq + 8]  = t2;
        *(float4*)&Bs[scol][skq + 12] = t3;
        __syncthreads();

        if (k0 + 64 < K) {                     // prefetch next tile (overlaps compute)
            t0 = *(const float4*)(wsrc + k0 + 64 + 0);
            t1 = *(const float4*)(wsrc + k0 + 64 + 4);
            t2 = *(const float4*)(wsrc + k0 + 64 + 8);
            t3 = *(const float4*)(wsrc + k0 + 64 + 12);
        }

        // Drain LDS once: lane's whole B column for this tile -> 64 VGPRs.
        float b[64];
        #pragma unroll
        for (int q = 0; q < 16; ++q)
            *(float4*)&b[q * 4] = *(const float4*)&Bs[lane][q << 2];

        // Pure scalar-load + FMA phases (16 k each), strictly ascending k.
        #pragma unroll
        for (int p = 0; p < 4; ++p) {
            float a[4][16];
            #pragma unroll
            for (int r = 0; r < 4; ++r) {
                const float* ap = arow + (size_t)r * K + k0 + (p << 4);
                #pragma unroll
                for (int q = 0; q < 4; ++q)
                    *(float4*)&a[r][q << 2] = *(const float4*)(ap + (q << 2));
            }
            #pragma unroll
            for (int kk = 0; kk < 16; ++kk) {
                #pragma unroll
                for (int r = 0; r < 4; ++r)
                    acc[r] = fmaf(a[r][kk], b[(p << 4) + kk], acc[r]);
            }
        }
    }

    // Epilogue: fp32 -> fp16 (RNE) -> 16 pulse bits. Lane-contiguous 64 B stores.
    #pragma unroll
    for (int r = 0; r < 4; ++r) {
        const unsigned short u = __half_as_ushort(__float2half_rn(acc[r]));
        float* o = out + ((size_t)(row0 + r) * COLS + (col0 + lane)) * 16;
        float4 q;
        q.x = (float)((u >> 0) & 1);
        q.y = (float)((u >> 1) & 1);
        q.z = (float)((u >> 2) & 1);
        q.w = (float)((u >> 3) & 1);
        *(float4*)(o + 0) = q;
        q.x = (float)((u >> 4) & 1);
        q.y = (float)((u >> 5) & 1);
        q.z = (float)((u >> 6) & 1);
        q.w = (float)((u >> 7) & 1);
        *(float4*)(o + 4) = q;
        q.x = (float)((u >> 8) & 1);
        q.y = (float)((u >> 9) & 1);
        q.z = (float)((u >> 10) & 1);
        q.w = (float)((u >> 11) & 1);
        *(float4*)(o + 8) = q;
        q.x = (float)((u >> 12) & 1);
        q.y = (float)((u >> 13) & 1);
        q.z = (float)((u >> 14) & 1);
        q.w = (float)((u >> 15) & 1);
        *(float4*)(o + 12) = q;
    }
}

extern "C" void kernel_launch(void* const* d_in, const int* in_sizes, int n_in,
                              void* d_out, int out_size, void* d_ws, size_t ws_size,
                              hipStream_t stream) {
    const float* xp = (const float*)d_in[0];   // [ROWS][K][16] bits
    const float* wp = (const float*)d_in[1];   // [COLS][K][16] bits
    float* outp = (float*)d_out;               // [ROWS][COLS][16] bits
    float* dec  = (float*)d_ws;                // NX + NW floats (3 MB)

    const int n_elem = NX + NW;                // 786432 -> 3072 blocks
    decode_k<<<n_elem / 256, 256, 0, stream>>>(xp, wp, dec);

    dim3 grid(COLS / 64, ROWS / 16);           // (8, 64) = 512 blocks
    gemm_k<<<grid, 256, 0, stream>>>(dec, outp);
}